// Round 1
// baseline (308.829 us; speedup 1.0000x reference)
//
#include <hip/hip_runtime.h>
#include <hip/hip_bf16.h>

// Embedding two-field gather + dot product.
// x: (B,2) int indices (field 0 in [0,100000), field 1 offset by +100000)
// table: (1100000, 64) float32
// out: (B,) float32, out[b] = dot(table[x[b,0]], table[x[b,1]+100000])

#define EMBED_DIM 64
#define FIELD1_OFFSET 100000

__global__ void MF_84722524880963_kernel(const int* __restrict__ x,
                                         const float* __restrict__ table,
                                         float* __restrict__ out,
                                         int B) {
    int gid = blockIdx.x * blockDim.x + threadIdx.x;
    int s = gid >> 6;      // one wave (64 lanes) per sample
    int lane = gid & 63;
    if (s >= B) return;

    // Row indices (int64 math not needed: max row 1,099,999; *64 fits in 32 bits
    // but use long for the byte-address safety anyway)
    long u = (long)x[2 * s];
    long v = (long)x[2 * s + 1] + FIELD1_OFFSET;

    // Coalesced: lane j reads element j of each 256B row
    float a = table[u * EMBED_DIM + lane];
    float b = table[v * EMBED_DIM + lane];
    float p = a * b;

    // 64-lane wave reduction
    #pragma unroll
    for (int off = 32; off > 0; off >>= 1)
        p += __shfl_down(p, off, 64);

    if (lane == 0) out[s] = p;
}

extern "C" void kernel_launch(void* const* d_in, const int* in_sizes, int n_in,
                              void* d_out, int out_size, void* d_ws, size_t ws_size,
                              hipStream_t stream) {
    const int* x = (const int*)d_in[0];          // (B,2) indices
    const float* table = (const float*)d_in[1];  // (1100000, 64) fp32
    float* out = (float*)d_out;                  // (B,) fp32
    int B = in_sizes[0] / 2;                     // 16384

    int threads = B * 64;                        // one wave per sample
    int block = 256;
    int grid = (threads + block - 1) / block;    // 4096 blocks
    MF_84722524880963_kernel<<<grid, block, 0, stream>>>(x, table, out, B);
}

// Round 2
// 307.887 us; speedup vs baseline: 1.0031x; 1.0031x over previous
//
#include <hip/hip_runtime.h>
#include <hip/hip_bf16.h>

// Embedding two-field gather + dot product.
// x: (B,2) int32 indices (field 0 in [0,100000), field 1 offset by +100000)
// table: (1100000, 64) float32
// out: (B,) float32, out[b] = dot(table[x[b,0]], table[x[b,1]+100000])
//
// Layout: 16 lanes per sample, each lane loads a float4 (16 B) -> one
// coalesced 256 B transaction per gathered row. 4 samples per wave.

#define FIELD1_OFFSET 100000

__global__ void MF_84722524880963_kernel(const int* __restrict__ x,
                                         const float* __restrict__ table,
                                         float* __restrict__ out,
                                         int B) {
    int gid = blockIdx.x * blockDim.x + threadIdx.x;
    int s   = gid >> 4;    // sample index (16 lanes per sample)
    int sub = gid & 15;    // lane within sample
    if (s >= B) return;

    int2 xi = ((const int2*)x)[s];            // both indices in one 8 B load
    long u = (long)xi.x;
    long v = (long)xi.y + FIELD1_OFFSET;

    const float4* t4 = (const float4*)table;  // row = 16 float4s
    float4 a = t4[u * 16 + sub];
    float4 b = t4[v * 16 + sub];
    float p = a.x * b.x + a.y * b.y + a.z * b.z + a.w * b.w;

    // reduce across the 16-lane segment
    p += __shfl_down(p, 8, 16);
    p += __shfl_down(p, 4, 16);
    p += __shfl_down(p, 2, 16);
    p += __shfl_down(p, 1, 16);

    if (sub == 0) out[s] = p;
}

extern "C" void kernel_launch(void* const* d_in, const int* in_sizes, int n_in,
                              void* d_out, int out_size, void* d_ws, size_t ws_size,
                              hipStream_t stream) {
    const int* x = (const int*)d_in[0];          // (B,2) int32
    const float* table = (const float*)d_in[1];  // (1100000, 64) fp32
    float* out = (float*)d_out;                  // (B,) fp32
    int B = in_sizes[0] / 2;                     // 16384

    int threads = B * 16;                        // 16 lanes per sample
    int block = 256;
    int grid = (threads + block - 1) / block;    // 1024 blocks
    MF_84722524880963_kernel<<<grid, block, 0, stream>>>(x, table, out, B);
}